// Round 6
// baseline (102.870 us; speedup 1.0000x reference)
//
#include <hip/hip_runtime.h>
#include <math.h>

#define RAD 5
#define SIDE 80
#define SLAB 6400      // 80*80
#define VOL 512000     // 80^3
#define NCH 8          // N*K
#define NCLS 4
#define TW 16          // tile extent along the convolved axis
#define NT 5           // tiles per axis (80/16)
#define CPART (SIDE*NT)        // 400 partials per channel
#define NBLK (NCH*SIDE*NT)     // 3200 blocks
#define Q 20           // float4 columns per 80-float row
#define TAS 24         // tA row stride in float4 (96 floats: 8-col pad both sides)
#define TBS 21         // tB/tile row stride in float4 (pad to spread bank groups)

// exp(-t^2/32) for t=-5..5 (unnormalized Gaussian, symmetric)
__constant__ float GW[11] = {
    0.45783336177161427f, 0.6065306597126334f, 0.7548396019890073f,
    0.8824969025845955f,  0.969233234476344f,  1.0f,
    0.969233234476344f,   0.8824969025845955f, 0.7548396019890073f,
    0.6065306597126334f,  0.45783336177161427f};

// Module-scope scratch (no d_ws dependence). All written-before-read each call.
__device__ float  g_bufT[(size_t)NCH * VOL];  // d+w-conv'd labels, [c][w][h][d]
__device__ float2 g_part1[NBLK];              // {S_ip, S_p} per K1 block
__device__ float2 g_part2[NBLK];              // {num, den} per K2 block

// K1: per (c, h, w-tile): channel sums + conv along D + conv along W,
// transposed store to g_bufT[c][w][h][d].
__global__ void __launch_bounds__(256) convdw_sums_kernel(
        const float* __restrict__ labels, const float* __restrict__ img) {
    const int blk = blockIdx.x;
    const int c   = blk / (SIDE * NT);
    const int rem = blk % (SIDE * NT);
    const int h   = rem / NT;
    const int w0  = (rem % NT) * TW;
    const int n   = c >> 2;

    __shared__ float4 tA[26 * TAS];   // labels rows w0-5..w0+20, 2-f4 pad each side
    __shared__ float4 tB[26 * TBS];   // d-conv output (20 f4 used per row)
    __shared__ float sm[8];

    // zero the d-pad columns only (f4 idx 0,1,22,23 per row)
    for (int i = threadIdx.x; i < 26 * 4; i += 256) {
        int r = i >> 2, j = i & 3;
        tA[r * TAS + ((j < 2) ? j : (20 + j))] = make_float4(0.f, 0.f, 0.f, 0.f);
    }
    // load labels rows; OOB halo rows store zero
    const float* labc = labels + ((size_t)c * SIDE + h) * SLAB;   // [w][d] slab
    for (int i = threadIdx.x; i < 26 * Q; i += 256) {
        int r = i / Q, q = i - r * Q;
        int w = w0 - RAD + r;
        float4 v = (w >= 0 && w < SIDE)
                     ? ((const float4*)(labc + (size_t)w * SIDE))[q]
                     : make_float4(0.f, 0.f, 0.f, 0.f);
        tA[r * TAS + 2 + q] = v;
    }
    __syncthreads();

    // channel sums over the central 16 rows (float4 both sides)
    float sip = 0.f, sp = 0.f;
    const float4* imgc4 = (const float4*)(img + ((((size_t)n * SIDE + h) * SIDE + w0) * SIDE));
    for (int i = threadIdx.x; i < TW * Q; i += 256) {
        int rl = i / Q, q = i - rl * Q;
        float4 l = tA[(rl + RAD) * TAS + 2 + q];
        float4 v = imgc4[i];
        sip += l.x * v.x + l.y * v.y + l.z * v.z + l.w * v.w;
        sp  += l.x + l.y + l.z + l.w;
    }

    // conv along D: register window, 5 b128 reads -> 4 outputs
    for (int i = threadIdx.x; i < 26 * Q; i += 256) {
        int r = i / Q, q = i - r * Q;
        const float4* row = &tA[r * TAS + q];   // f4 idx q..q+4 = d in [4q-8, 4q+11]
        float a[20];
        #pragma unroll
        for (int j = 0; j < 5; ++j) {
            float4 v = row[j];
            a[4 * j] = v.x; a[4 * j + 1] = v.y; a[4 * j + 2] = v.z; a[4 * j + 3] = v.w;
        }
        float4 o;
        float s0 = 0.f, s1 = 0.f, s2 = 0.f, s3 = 0.f;
        #pragma unroll
        for (int t = 0; t < 11; ++t) {
            float g = GW[t];
            s0 += g * a[t + 3]; s1 += g * a[t + 4];
            s2 += g * a[t + 5]; s3 += g * a[t + 6];
        }
        o.x = s0; o.y = s1; o.z = s2; o.w = s3;
        tB[r * TBS + q] = o;
    }

    // block-reduce the sums (no atomics: per-block slot)
    #pragma unroll
    for (int off = 32; off > 0; off >>= 1) {
        sip += __shfl_down(sip, off);
        sp  += __shfl_down(sp, off);
    }
    const int lane = threadIdx.x & 63;
    const int wid  = threadIdx.x >> 6;
    if (lane == 0) { sm[wid * 2] = sip; sm[wid * 2 + 1] = sp; }
    __syncthreads();   // tB complete + sm visible
    if (threadIdx.x == 0)
        g_part1[blk] = make_float2(sm[0] + sm[2] + sm[4] + sm[6],
                                   sm[1] + sm[3] + sm[5] + sm[7]);

    // conv along W (11 b128 taps -> 4 outputs) + transposed float4 store
    float* outc = g_bufT + (size_t)c * VOL + (size_t)h * SIDE;
    for (int i = threadIdx.x; i < TW * Q; i += 256) {
        int rl = i / Q, q = i - rl * Q;
        float sx = 0.f, sy = 0.f, sz = 0.f, sw = 0.f;
        #pragma unroll
        for (int t = 0; t < 11; ++t) {
            float g = GW[t];
            float4 v = tB[(rl + t) * TBS + q];
            sx += g * v.x; sy += g * v.y; sz += g * v.z; sw += g * v.w;
        }
        ((float4*)(outc + (size_t)(w0 + rl) * SLAB))[q] = make_float4(sx, sy, sz, sw);
    }
}

// K2: per (c, w, h-tile): conv along H of g_bufT + fused weight + dot with labels.
// num_c = sum (G*lab)·lab·wgt ; den_c = sum (G*lab)·wgt ; wgt = exp(-(img-mean_c)^4)
__global__ void __launch_bounds__(256) convh_dot_kernel(
        const float* __restrict__ labels, const float* __restrict__ img) {
    const int blk = blockIdx.x;
    const int c   = blk / (SIDE * NT);
    const int rem = blk % (SIDE * NT);
    const int w   = rem / NT;
    const int h0  = (rem % NT) * TW;
    const int n   = c >> 2;

    __shared__ float4 tile[26 * TBS];  // g_bufT rows h0-5..h0+20 at fixed (c,w)
    __shared__ float sm[8];
    __shared__ float s_mean;

    // per-channel mean from K1 partials (redundant per block; L2-resident)
    float a = 0.f, b = 0.f;
    for (int t = threadIdx.x; t < CPART; t += 256) {
        float2 p = g_part1[c * CPART + t];
        a += p.x; b += p.y;
    }
    #pragma unroll
    for (int off = 32; off > 0; off >>= 1) {
        a += __shfl_down(a, off);
        b += __shfl_down(b, off);
    }
    const int lane = threadIdx.x & 63;
    const int wid  = threadIdx.x >> 6;
    if (lane == 0) { sm[wid * 2] = a; sm[wid * 2 + 1] = b; }

    // load tile (rows contiguous in g_bufT layout), zero OOB halo
    const float4* bc4 = (const float4*)(g_bufT + (size_t)c * VOL + (size_t)w * SLAB);
    for (int i = threadIdx.x; i < 26 * Q; i += 256) {
        int r = i / Q, q = i - r * Q;
        int hh = h0 - RAD + r;
        float4 v = (hh >= 0 && hh < SIDE) ? bc4[hh * Q + q]
                                          : make_float4(0.f, 0.f, 0.f, 0.f);
        tile[r * TBS + q] = v;
    }
    __syncthreads();
    if (threadIdx.x == 0)
        s_mean = (sm[0] + sm[2] + sm[4] + sm[6]) /
                 (sm[1] + sm[3] + sm[5] + sm[7] + 5.12f);   // VOL*EPS_MEAN
    __syncthreads();
    const float mean = s_mean;

    const float4* labp4 = (const float4*)(labels + (size_t)c * VOL);
    const float4* imgp4 = (const float4*)(img + (size_t)n * VOL);
    float num = 0.f, den = 0.f;
    for (int i = threadIdx.x; i < TW * Q; i += 256) {
        int hl = i / Q, q = i - hl * Q;
        float sx = 0.f, sy = 0.f, sz = 0.f, sw = 0.f;
        #pragma unroll
        for (int t = 0; t < 11; ++t) {
            float g = GW[t];
            float4 v = tile[(hl + t) * TBS + q];
            sx += g * v.x; sy += g * v.y; sz += g * v.z; sw += g * v.w;
        }
        size_t gi = ((size_t)(h0 + hl) * SIDE + w) * Q + q;   // float4 index
        float4 l = labp4[gi];
        float4 v = imgp4[gi];
        float d0 = v.x - mean, d1 = v.y - mean, d2 = v.z - mean, d3 = v.w - mean;
        float q0 = d0 * d0, q1 = d1 * d1, q2 = d2 * d2, q3 = d3 * d3;
        float w0_ = __expf(-q0 * q0), w1_ = __expf(-q1 * q1);
        float w2_ = __expf(-q2 * q2), w3_ = __expf(-q3 * q3);
        num += sx * l.x * w0_ + sy * l.y * w1_ + sz * l.z * w2_ + sw * l.w * w3_;
        den += sx * w0_ + sy * w1_ + sz * w2_ + sw * w3_;
    }
    #pragma unroll
    for (int off = 32; off > 0; off >>= 1) {
        num += __shfl_down(num, off);
        den += __shfl_down(den, off);
    }
    if (lane == 0) { sm[wid * 2] = num; sm[wid * 2 + 1] = den; }
    __syncthreads();
    if (threadIdx.x == 0)
        g_part2[blk] = make_float2(sm[0] + sm[2] + sm[4] + sm[6],
                                   sm[1] + sm[3] + sm[5] + sm[7]);
}

// K3: reduce per-block partials -> per-channel ratio -> loss scalar
__global__ void __launch_bounds__(256) final_kernel(float* __restrict__ out) {
    __shared__ float sm[8];
    __shared__ float cn[NCH], cd[NCH];
    const int lane = threadIdx.x & 63;
    const int wid  = threadIdx.x >> 6;
    for (int c = 0; c < NCH; ++c) {
        float a = 0.f, b = 0.f;
        for (int t = threadIdx.x; t < CPART; t += 256) {
            float2 p = g_part2[c * CPART + t];
            a += p.x; b += p.y;
        }
        #pragma unroll
        for (int off = 32; off > 0; off >>= 1) {
            a += __shfl_down(a, off);
            b += __shfl_down(b, off);
        }
        if (lane == 0) { sm[wid * 2] = a; sm[wid * 2 + 1] = b; }
        __syncthreads();
        if (threadIdx.x == 0) {
            cn[c] = sm[0] + sm[2] + sm[4] + sm[6];
            cd[c] = sm[1] + sm[3] + sm[5] + sm[7];
        }
        __syncthreads();
    }
    if (threadIdx.x == 0) {
        float loss = 0.f;
        for (int k = 0; k < NCLS; ++k) {
            float r0 = cn[k]        / (cd[k]        + 1e-6f);
            float r1 = cn[NCLS + k] / (cd[NCLS + k] + 1e-6f);
            loss += 0.5f * (fabsf(r0) + fabsf(r1));   // mean over N=2, sum over K
        }
        out[0] = (float)NCLS - loss;
    }
}

extern "C" void kernel_launch(void* const* d_in, const int* in_sizes, int n_in,
                              void* d_out, int out_size, void* d_ws, size_t ws_size,
                              hipStream_t stream) {
    const float* labels = (const float*)d_in[0];   // (2,4,80,80,80) f32
    const float* img    = (const float*)d_in[1];   // (2,1,80,80,80) f32
    float* out = (float*)d_out;                    // 1 float
    (void)d_ws; (void)ws_size;                     // module-scope scratch

    hipLaunchKernelGGL(convdw_sums_kernel, dim3(NBLK), dim3(256), 0, stream, labels, img);
    hipLaunchKernelGGL(convh_dot_kernel,   dim3(NBLK), dim3(256), 0, stream, labels, img);
    hipLaunchKernelGGL(final_kernel,       dim3(1),    dim3(256), 0, stream, out);
}